// Round 8
// baseline (187.795 us; speedup 1.0000x reference)
//
#include <hip/hip_runtime.h>

// Problem constants
#define NB 2
#define DD 192
#define HH 192
#define WW 192
#define HWSZ (HH * WW)
#define C1F 0.0001f
#define C2F 0.0009f

// Tiling: 16(H) x 32(W) outputs per block-slice, 256 threads, stream D.
#define TH 16
#define TW 32
#define CHUNK 24
#define TSTEPS (CHUNK + 10)          // 34
#define NCH (DD / CHUNK)             // 8
#define NTH (HH / TH)                // 12
#define NTW (WW / TW)                // 6
#define NBLK (NB * NCH * NTH * NTW)  // 1152

#define SROWS (TH + 10)              // 26 staged/W-blurred rows
#define SCOLS 42                     // staged cols (w0-5 .. w0+36)
#define SQ 53                        // s4 row stride in quads (padded positions)
#define TQ 40                        // t4 row stride in quads
#define NSTG (SROWS * SCOLS)         // 1092 stage tasks
#define NWT (SROWS * (TW / 4))       // 208 W-blur tasks

// In-row quad padding: quad j stored at position j + (j>>2).
// Read positions are = j mod 5 in {0..3}; pad slots (pos%5==4) never read.
__device__ __forceinline__ constexpr int QPOS(int j) { return j + (j >> 2); }

// Gaussian weights, WIN=11, sigma=1.5
#define KWLIST { 0.00102838f, 0.00759876f, 0.03600077f, 0.10936071f, 0.21300556f, \
                 0.26601172f, 0.21300556f, 0.10936071f, 0.03600077f, 0.00759876f, 0.00102838f }

// SSIM from 4 packed stats: mu1, mu2, A=blur((x+y)^2), Bm=blur((x-y)^2).
__device__ __forceinline__ float ssim_val(float mu1, float mu2, float A, float Bm) {
  const float mu1sq = mu1 * mu1, mu2sq = mu2 * mu2, mu12 = mu1 * mu2;
  const float num = (2.f * mu12 + C1F) * (0.5f * (A - Bm) - 2.f * mu12 + C2F);
  const float den = (mu1sq + mu2sq + C1F) * (0.5f * (A + Bm) - mu1sq - mu2sq + C2F);
  return num * __builtin_amdgcn_rcpf(den);
}

__global__ __launch_bounds__(256) void ssim_fused(
    const float* __restrict__ x, const float* __restrict__ y,
    float* __restrict__ partials) {
  const float KW[11] = KWLIST;

  int bid = blockIdx.x;
  const int tw = bid % NTW; bid /= NTW;
  const int th = bid % NTH; bid /= NTH;
  const int c  = bid % NCH; bid /= NCH;
  const int b  = bid;
  const int h0 = th * TH, w0 = tw * TW, c0 = c * CHUNK;

  __shared__ float4 s4[SROWS][SQ];   // staged {x, y, (x+y)^2, (x-y)^2}, quad-padded
  __shared__ float4 t4[SROWS][TQ];   // W-blurred 4 fields, quad-padded

  const int tid = threadIdx.x;
  const int cl  = tid & 31;            // own W col
  const int rg  = tid >> 5;            // 0..7 row-group
  const int r0  = 2 * rg;              // own output rows r0, r0+1
  const int clp = QPOS(cl);            // padded read position for H-blur

  // ---- hoisted stage-task addressing: 1092 scalar tasks, 5 rounds ----
  int  sIdx[5], sOff[5];
  bool sOk[5];
#pragma unroll
  for (int k = 0; k < 5; ++k) {
    const int q = tid + 256 * k;
    const bool act = (q < NSTG);
    const int row = q / SCOLS, col = q % SCOLS;
    const int gh = h0 - 5 + row, gw = w0 - 5 + col;
    sOk[k]  = act && (unsigned)gh < (unsigned)HH && (unsigned)gw < (unsigned)WW;
    sIdx[k] = row * SQ + QPOS(col);
    sOff[k] = gh * WW + gw;
  }
  // W-blur task addressing (208 tasks)
  const bool wAct = (tid < NWT);
  const int  wr = tid >> 3;            // 0..25
  const int  wq = tid & 7;             // 0..7 (4-output group)

  // zero-init s4 once (OOB cols + pad slots stay zero all kernel)
  {
    const float4 z = make_float4(0.f, 0.f, 0.f, 0.f);
    for (int q = tid; q < SROWS * SQ; q += 256) (&s4[0][0])[q] = z;
  }
  __syncthreads();

  const float* xb = x + (size_t)b * DD * HWSZ;
  const float* yb = y + (size_t)b * DD * HWSZ;

  // Ring accumulators (2 output rows x 4 fields x 11 slots), compile-time idx.
  float pend0[4][11], pend1[4][11];
#pragma unroll
  for (int f = 0; f < 4; ++f)
#pragma unroll
    for (int i = 0; i < 11; ++i) { pend0[f][i] = 0.f; pend1[f][i] = 0.f; }

  float px[5], py[5];
#pragma unroll
  for (int k = 0; k < 5; ++k) { px[k] = 0.f; py[k] = 0.f; }

  // pre-loop prefetch of slice t=0 (d = c0-5), only valid for c>0
  if (c0 >= 5) {
    const float* xs = xb + (size_t)(c0 - 5) * HWSZ;
    const float* ys = yb + (size_t)(c0 - 5) * HWSZ;
#pragma unroll
    for (int k = 0; k < 5; ++k)
      if (sOk[k]) { px[k] = xs[sOff[k]]; py[k] = ys[sOff[k]]; }
  }

  float lsum = 0.f;
  int p = 0;   // t mod 11 (wave-uniform)

  for (int t = 0; t < TSTEPS; ++t) {
    const int d = c0 - 5 + t;
    const bool dv = (d >= 0) && (d < DD);   // block-uniform

    if (dv) {
      // ---- stage prefetched slice ----
#pragma unroll
      for (int k = 0; k < 5; ++k)
        if (sOk[k]) {
          const float xx = px[k], yy = py[k];
          const float sm = xx + yy, df = xx - yy;
          (&s4[0][0])[sIdx[k]] = make_float4(xx, yy, sm * sm, df * df);
        }
    }
    // ---- prefetch slice t+1 (latency hidden under W/H compute) ----
    {
      const int dn = d + 1;
      if ((t + 1) < TSTEPS && dn >= 0 && dn < DD) {
        const float* xs = xb + (size_t)dn * HWSZ;
        const float* ys = yb + (size_t)dn * HWSZ;
#pragma unroll
        for (int k = 0; k < 5; ++k)
          if (sOk[k]) { px[k] = xs[sOff[k]]; py[k] = ys[sOff[k]]; }
      }
    }

    float4 B0 = make_float4(0.f, 0.f, 0.f, 0.f);
    float4 B1 = B0;

    if (dv) {
      __syncthreads();
      // ---- W-blur: 4 outputs per task, padded reads (stride 5 quads ->
      // bank bases {0,20,8,28,16,4,24,12}: conflict-free) ----
      if (wAct) {
        const float4* srow = &s4[wr][0];
        float4 a0 = make_float4(0.f, 0.f, 0.f, 0.f), a1 = a0, a2 = a0, a3 = a0;
#pragma unroll
        for (int u = 0; u < 14; ++u) {
          const float4 v = srow[5 * wq + u + (u >> 2)];   // QPOS(4wq+u)
          if (u <= 10)           { const float k = KW[u];     a0.x += k*v.x; a0.y += k*v.y; a0.z += k*v.z; a0.w += k*v.w; }
          if (u >= 1 && u <= 11) { const float k = KW[u - 1]; a1.x += k*v.x; a1.y += k*v.y; a1.z += k*v.z; a1.w += k*v.w; }
          if (u >= 2 && u <= 12) { const float k = KW[u - 2]; a2.x += k*v.x; a2.y += k*v.y; a2.z += k*v.z; a2.w += k*v.w; }
          if (u >= 3)            { const float k = KW[u - 3]; a3.x += k*v.x; a3.y += k*v.y; a3.z += k*v.z; a3.w += k*v.w; }
        }
        float4* trow = &t4[wr][0];
        trow[5 * wq + 0] = a0;   // QPOS(4wq+i) = 5wq+i, stride-5: conflict-free
        trow[5 * wq + 1] = a1;
        trow[5 * wq + 2] = a2;
        trow[5 * wq + 3] = a3;
      }
      __syncthreads();

      // ---- H-blur: 2 output rows per thread (consecutive-quad reads: <=2-way) ----
#pragma unroll
      for (int u = 0; u < 12; ++u) {
        const float4 v = t4[r0 + u][clp];
        if (u <= 10) { const float k = KW[u];     B0.x += k*v.x; B0.y += k*v.y; B0.z += k*v.z; B0.w += k*v.w; }
        if (u >= 1)  { const float k = KW[u - 1]; B1.x += k*v.x; B1.y += k*v.y; B1.z += k*v.z; B1.w += k*v.w; }
      }
    }

    // ---- D-ring: compile-time slots via switch on p = t % 11 ----
#define RING_CASE(P)                                                        \
    case P: {                                                               \
      if (dv) {                                                             \
        _Pragma("unroll")                                                   \
        for (int kk = 0; kk < 11; ++kk) {                                   \
          const int   sl = (P + 1 + kk) % 11;                               \
          const float wg = KW[kk];                                          \
          pend0[0][sl] += wg * B0.x; pend0[1][sl] += wg * B0.y;             \
          pend0[2][sl] += wg * B0.z; pend0[3][sl] += wg * B0.w;             \
          pend1[0][sl] += wg * B1.x; pend1[1][sl] += wg * B1.y;             \
          pend1[2][sl] += wg * B1.z; pend1[3][sl] += wg * B1.w;             \
        }                                                                   \
      }                                                                     \
      const int sc = (P + 1) % 11;                                          \
      if (t >= 10) {                                                        \
        lsum += ssim_val(pend0[0][sc], pend0[1][sc], pend0[2][sc], pend0[3][sc]); \
        lsum += ssim_val(pend1[0][sc], pend1[1][sc], pend1[2][sc], pend1[3][sc]); \
      }                                                                     \
      pend0[0][sc] = 0.f; pend0[1][sc] = 0.f;                               \
      pend0[2][sc] = 0.f; pend0[3][sc] = 0.f;                               \
      pend1[0][sc] = 0.f; pend1[1][sc] = 0.f;                               \
      pend1[2][sc] = 0.f; pend1[3][sc] = 0.f;                               \
    } break;

    switch (p) {
      RING_CASE(0) RING_CASE(1) RING_CASE(2) RING_CASE(3) RING_CASE(4)
      RING_CASE(5) RING_CASE(6) RING_CASE(7) RING_CASE(8) RING_CASE(9)
      RING_CASE(10)
    }
#undef RING_CASE
    p = (p + 1 == 11) ? 0 : p + 1;
  }

  // ---- block reduction: 4 waves ----
  for (int off = 32; off > 0; off >>= 1) lsum += __shfl_down(lsum, off, 64);
  __shared__ float wsum[4];
  if ((tid & 63) == 0) wsum[tid >> 6] = lsum;
  __syncthreads();
  if (tid == 0) partials[blockIdx.x] = wsum[0] + wsum[1] + wsum[2] + wsum[3];
}

// ---------------------------------------------------------------------------
// Final reduction: NBLK partials -> mean (deterministic, double).
// ---------------------------------------------------------------------------
__global__ __launch_bounds__(256) void ssim_reduce(
    const float* __restrict__ partials, float* __restrict__ out) {
  __shared__ double sd[256];
  double a = 0.0;
  for (int i = threadIdx.x; i < NBLK; i += 256) a += (double)partials[i];
  sd[threadIdx.x] = a;
  __syncthreads();
  for (int s = 128; s > 0; s >>= 1) {
    if ((int)threadIdx.x < s) sd[threadIdx.x] += sd[threadIdx.x + s];
    __syncthreads();
  }
  if (threadIdx.x == 0) {
    out[0] = (float)(sd[0] / (double)((size_t)NB * DD * HH * WW));
  }
}

extern "C" void kernel_launch(void* const* d_in, const int* in_sizes, int n_in,
                              void* d_out, int out_size, void* d_ws, size_t ws_size,
                              hipStream_t stream) {
  const float* img1 = (const float*)d_in[0];
  const float* img2 = (const float*)d_in[1];
  float* out = (float*)d_out;
  float* partials = (float*)d_ws;   // NBLK floats

  ssim_fused<<<NBLK, 256, 0, stream>>>(img1, img2, partials);
  ssim_reduce<<<1, 256, 0, stream>>>(partials, out);
}

// Round 9
// 167.146 us; speedup vs baseline: 1.1235x; 1.1235x over previous
//
#include <hip/hip_runtime.h>

// Problem constants
#define NB 2
#define DD 192
#define HH 192
#define WW 192
#define HWSZ (HH * WW)
#define C1F 0.0001f
#define C2F 0.0009f

// Tiling: 16(H) x 32(W) outputs per block-slice, 256 threads, stream D.
#define TH 16
#define TW 32
#define CHUNK 24
#define TSTEPS (CHUNK + 10)          // 34
#define NCH (DD / CHUNK)             // 8
#define NTH (HH / TH)                // 12
#define NTW (WW / TW)                // 6
#define NBLK (NB * NCH * NTH * NTW)  // 1152

#define SROWS (TH + 10)              // 26 staged/W-blurred rows
#define SCOLS 42                     // staged cols (w0-5 .. w0+36)
#define SQ 43                        // s4 row stride in quads (odd)
#define TQ 36                        // t4 row stride in quads (== 4 mod 8)
#define NSTG (SROWS * SCOLS)         // 1092 stage tasks
#define NWT (SROWS * (TW / 4))       // 208 W-blur tasks

// Gaussian weights, WIN=11, sigma=1.5
#define KWLIST { 0.00102838f, 0.00759876f, 0.03600077f, 0.10936071f, 0.21300556f, \
                 0.26601172f, 0.21300556f, 0.10936071f, 0.03600077f, 0.00759876f, 0.00102838f }

// SSIM from 4 packed stats: mu1, mu2, A=blur((x+y)^2), Bm=blur((x-y)^2).
__device__ __forceinline__ float ssim_val(float mu1, float mu2, float A, float Bm) {
  const float mu1sq = mu1 * mu1, mu2sq = mu2 * mu2, mu12 = mu1 * mu2;
  const float num = (2.f * mu12 + C1F) * (0.5f * (A - Bm) - 2.f * mu12 + C2F);
  const float den = (mu1sq + mu2sq + C1F) * (0.5f * (A + Bm) - mu1sq - mu2sq + C2F);
  return num * __builtin_amdgcn_rcpf(den);
}

__global__ __launch_bounds__(256) void ssim_fused(
    const float* __restrict__ x, const float* __restrict__ y,
    float* __restrict__ partials) {
  const float KW[11] = KWLIST;

  int bid = blockIdx.x;
  const int tw = bid % NTW; bid /= NTW;
  const int th = bid % NTH; bid /= NTH;
  const int c  = bid % NCH; bid /= NCH;
  const int b  = bid;
  const int h0 = th * TH, w0 = tw * TW, c0 = c * CHUNK;

  __shared__ float4 s4[SROWS][SQ];   // staged {x, y, (x+y)^2, (x-y)^2} per pixel
  __shared__ float4 t4[SROWS][TQ];   // W-blurred 4 fields (store-rotated layout)

  const int tid = threadIdx.x;
  const int cl  = tid & 31;            // own W col
  const int rg  = tid >> 5;            // 0..7 row-group
  const int r0  = 2 * rg;              // own output rows r0, r0+1
  // t4 store-rotation inverse: pixel cl lives at position
  //   (cl & ~3) | ((cl + (cl>>2)) & 3)
  const int clp2 = (cl & ~3) | (((cl & 3) + (cl >> 2)) & 3);

  // ---- hoisted stage-task addressing: 1092 scalar tasks, 5 rounds ----
  int  sIdx[5], sOff[5];
  bool sOk[5];
#pragma unroll
  for (int k = 0; k < 5; ++k) {
    const int q = tid + 256 * k;
    const bool act = (q < NSTG);
    const int row = q / SCOLS, col = q % SCOLS;
    const int gh = h0 - 5 + row, gw = w0 - 5 + col;
    sOk[k]  = act && (unsigned)gh < (unsigned)HH && (unsigned)gw < (unsigned)WW;
    sIdx[k] = row * SQ + col;
    sOff[k] = gh * WW + gw;
  }
  // W-blur task addressing (208 tasks); rotated store positions (2-way free)
  const bool wAct = (tid < NWT);
  const int  wr = tid >> 3;            // 0..25
  const int  wq = tid & 7;             // 0..7 (4-output group)
  const int  tBase = wr * TQ + 4 * wq;
  const int  st0 = tBase + ((0 + wq) & 3);
  const int  st1 = tBase + ((1 + wq) & 3);
  const int  st2 = tBase + ((2 + wq) & 3);
  const int  st3 = tBase + ((3 + wq) & 3);

  // zero-init s4 once (OOB cols stay zero all kernel)
  {
    const float4 z = make_float4(0.f, 0.f, 0.f, 0.f);
    for (int q = tid; q < SROWS * SQ; q += 256) (&s4[0][0])[q] = z;
  }
  __syncthreads();

  const float* xb = x + (size_t)b * DD * HWSZ;
  const float* yb = y + (size_t)b * DD * HWSZ;

  // Ring accumulators (2 output rows x 4 fields x 11 slots), compile-time idx.
  float pend0[4][11], pend1[4][11];
#pragma unroll
  for (int f = 0; f < 4; ++f)
#pragma unroll
    for (int i = 0; i < 11; ++i) { pend0[f][i] = 0.f; pend1[f][i] = 0.f; }

  float px[5], py[5];
#pragma unroll
  for (int k = 0; k < 5; ++k) { px[k] = 0.f; py[k] = 0.f; }

  // pre-loop prefetch of slice t=0 (d = c0-5), only valid for c>0
  if (c0 >= 5) {
    const float* xs = xb + (size_t)(c0 - 5) * HWSZ;
    const float* ys = yb + (size_t)(c0 - 5) * HWSZ;
#pragma unroll
    for (int k = 0; k < 5; ++k)
      if (sOk[k]) { px[k] = xs[sOff[k]]; py[k] = ys[sOff[k]]; }
  }

  float lsum = 0.f;
  int p = 0;   // t mod 11 (wave-uniform)

  for (int t = 0; t < TSTEPS; ++t) {
    const int d = c0 - 5 + t;
    const bool dv = (d >= 0) && (d < DD);   // block-uniform

    if (dv) {
      // ---- stage prefetched slice (consecutive-lane b128 writes) ----
#pragma unroll
      for (int k = 0; k < 5; ++k)
        if (sOk[k]) {
          const float xx = px[k], yy = py[k];
          const float sm = xx + yy, df = xx - yy;
          (&s4[0][0])[sIdx[k]] = make_float4(xx, yy, sm * sm, df * df);
        }
    }
    // ---- prefetch slice t+1 (latency hidden under W/H compute) ----
    {
      const int dn = d + 1;
      if ((t + 1) < TSTEPS && dn >= 0 && dn < DD) {
        const float* xs = xb + (size_t)dn * HWSZ;
        const float* ys = yb + (size_t)dn * HWSZ;
#pragma unroll
        for (int k = 0; k < 5; ++k)
          if (sOk[k]) { px[k] = xs[sOff[k]]; py[k] = ys[sOff[k]]; }
      }
    }

    float4 B0 = make_float4(0.f, 0.f, 0.f, 0.f);
    float4 B1 = B0;

    if (dv) {
      __syncthreads();
      // ---- W-blur: 4 outputs per task via sliding window (14 reads) ----
      if (wAct) {
        const float4* srow = &s4[wr][0];
        float4 a0 = make_float4(0.f, 0.f, 0.f, 0.f), a1 = a0, a2 = a0, a3 = a0;
#pragma unroll
        for (int u = 0; u < 14; ++u) {
          const float4 v = srow[4 * wq + u];
          if (u <= 10)           { const float k = KW[u];     a0.x += k*v.x; a0.y += k*v.y; a0.z += k*v.z; a0.w += k*v.w; }
          if (u >= 1 && u <= 11) { const float k = KW[u - 1]; a1.x += k*v.x; a1.y += k*v.y; a1.z += k*v.z; a1.w += k*v.w; }
          if (u >= 2 && u <= 12) { const float k = KW[u - 2]; a2.x += k*v.x; a2.y += k*v.y; a2.z += k*v.z; a2.w += k*v.w; }
          if (u >= 3)            { const float k = KW[u - 3]; a3.x += k*v.x; a3.y += k*v.y; a3.z += k*v.z; a3.w += k*v.w; }
        }
        // rotated stores: position 4wq+(i+wq)%4  -> 2-way (free) bank pattern
        float4* tb = &t4[0][0];
        tb[st0] = a0; tb[st1] = a1; tb[st2] = a2; tb[st3] = a3;
      }
      __syncthreads();

      // ---- H-blur: 2 output rows per thread; un-permuted read col clp2 ----
#pragma unroll
      for (int u = 0; u < 12; ++u) {
        const float4 v = t4[r0 + u][clp2];
        if (u <= 10) { const float k = KW[u];     B0.x += k*v.x; B0.y += k*v.y; B0.z += k*v.z; B0.w += k*v.w; }
        if (u >= 1)  { const float k = KW[u - 1]; B1.x += k*v.x; B1.y += k*v.y; B1.z += k*v.z; B1.w += k*v.w; }
      }
    }

    // ---- D-ring: compile-time slots via switch on p = t % 11 ----
#define RING_CASE(P)                                                        \
    case P: {                                                               \
      if (dv) {                                                             \
        _Pragma("unroll")                                                   \
        for (int kk = 0; kk < 11; ++kk) {                                   \
          const int   sl = (P + 1 + kk) % 11;                               \
          const float wg = KW[kk];                                          \
          pend0[0][sl] += wg * B0.x; pend0[1][sl] += wg * B0.y;             \
          pend0[2][sl] += wg * B0.z; pend0[3][sl] += wg * B0.w;             \
          pend1[0][sl] += wg * B1.x; pend1[1][sl] += wg * B1.y;             \
          pend1[2][sl] += wg * B1.z; pend1[3][sl] += wg * B1.w;             \
        }                                                                   \
      }                                                                     \
      const int sc = (P + 1) % 11;                                          \
      if (t >= 10) {                                                        \
        lsum += ssim_val(pend0[0][sc], pend0[1][sc], pend0[2][sc], pend0[3][sc]); \
        lsum += ssim_val(pend1[0][sc], pend1[1][sc], pend1[2][sc], pend1[3][sc]); \
      }                                                                     \
      pend0[0][sc] = 0.f; pend0[1][sc] = 0.f;                               \
      pend0[2][sc] = 0.f; pend0[3][sc] = 0.f;                               \
      pend1[0][sc] = 0.f; pend1[1][sc] = 0.f;                               \
      pend1[2][sc] = 0.f; pend1[3][sc] = 0.f;                               \
    } break;

    switch (p) {
      RING_CASE(0) RING_CASE(1) RING_CASE(2) RING_CASE(3) RING_CASE(4)
      RING_CASE(5) RING_CASE(6) RING_CASE(7) RING_CASE(8) RING_CASE(9)
      RING_CASE(10)
    }
#undef RING_CASE
    p = (p + 1 == 11) ? 0 : p + 1;
  }

  // ---- block reduction: 4 waves ----
  for (int off = 32; off > 0; off >>= 1) lsum += __shfl_down(lsum, off, 64);
  __shared__ float wsum[4];
  if ((tid & 63) == 0) wsum[tid >> 6] = lsum;
  __syncthreads();
  if (tid == 0) partials[blockIdx.x] = wsum[0] + wsum[1] + wsum[2] + wsum[3];
}

// ---------------------------------------------------------------------------
// Final reduction: NBLK partials -> mean (deterministic, double).
// ---------------------------------------------------------------------------
__global__ __launch_bounds__(256) void ssim_reduce(
    const float* __restrict__ partials, float* __restrict__ out) {
  __shared__ double sd[256];
  double a = 0.0;
  for (int i = threadIdx.x; i < NBLK; i += 256) a += (double)partials[i];
  sd[threadIdx.x] = a;
  __syncthreads();
  for (int s = 128; s > 0; s >>= 1) {
    if ((int)threadIdx.x < s) sd[threadIdx.x] += sd[threadIdx.x + s];
    __syncthreads();
  }
  if (threadIdx.x == 0) {
    out[0] = (float)(sd[0] / (double)((size_t)NB * DD * HH * WW));
  }
}

extern "C" void kernel_launch(void* const* d_in, const int* in_sizes, int n_in,
                              void* d_out, int out_size, void* d_ws, size_t ws_size,
                              hipStream_t stream) {
  const float* img1 = (const float*)d_in[0];
  const float* img2 = (const float*)d_in[1];
  float* out = (float*)d_out;
  float* partials = (float*)d_ws;   // NBLK floats

  ssim_fused<<<NBLK, 256, 0, stream>>>(img1, img2, partials);
  ssim_reduce<<<1, 256, 0, stream>>>(partials, out);
}